// Round 1
// baseline (262.301 us; speedup 1.0000x reference)
//
#include <hip/hip_runtime.h>
#include <cstdint>

// Problem constants: B=32, T=D=256, rows R = B*T = 8192, K = 256.
#define R_TOT 8192
#define KD    256
#define SLOT  ((size_t)R_TOT * KD)            // ushorts per bf16 matrix (2,097,152)
#define MATS_OFF 65792                        // bytes: norms area = (64 + 2*8192) f32
#define PART_OFF (MATS_OFF + (size_t)4 * SLOT * 2)  // 16,843,008
// ws usage: norms (64+16384 f32) + 4 bf16 mats (16 MB) + 2 f32 partials (16 MB) ~= 32.1 MB

typedef float f32x4 __attribute__((ext_vector_type(4)));
typedef short s16x8 __attribute__((ext_vector_type(8)));   // 8 bf16 (4 VGPRs)

__device__ __forceinline__ unsigned short bf16rne(float x){
  union { float f; uint32_t u; } c; c.f = x;
  return (unsigned short)((c.u + 0x7fffu + ((c.u >> 16) & 1u)) >> 16);
}

// nrm layout (f32): [0,32) inv_vnV, [32,64) inv_vnA, [64,64+8192) inv_cnV, then inv_cnA
__global__ void norms_k(const float* __restrict__ V, const float* __restrict__ A,
                        float* __restrict__ nrm){
  const int j = blockIdx.x, ten = blockIdx.y, s = threadIdx.x;
  const float* X = (ten ? A : V) + (size_t)j * (256 * 256) + s;
  float c = 0.f;
  #pragma unroll 8
  for (int t = 0; t < 256; ++t){ float v = X[(size_t)t * 256]; c += v * v; }
  nrm[64 + ten * 8192 + (j << 8) + s] = rsqrtf(c + 1e-18f);   // 1/colnorm
  __shared__ float red[256];
  red[s] = c; __syncthreads();
  for (int off = 128; off > 0; off >>= 1){
    if (s < off) red[s] += red[s + off];
    __syncthreads();
  }
  if (s == 0) nrm[ten * 32 + j] = rsqrtf(red[0] + 1e-18f);    // 1/frobenius
}

// mats slots: 0=V1 (V*ivnV, dir0 rows), 1=A1 (A*icnA, dir0 cols),
//             2=A2 (A*ivnA, dir1 rows), 3=V2 (V*icnV, dir1 cols)
__global__ void scale_k(const float* __restrict__ V, const float* __restrict__ A,
                        const float* __restrict__ nrm, unsigned short* __restrict__ mats){
  const int idx = blockIdx.x * 256 + threadIdx.x;   // 0..1048575 (float4 units, 2 tensors)
  const int ten = idx >> 19;
  const int r   = idx & 0x7ffff;                    // float4 index within tensor
  const int j   = r >> 14;                          // batch
  const int row = (r >> 6) & 255;                   // row within batch
  const float4 v = ((const float4*)(ten ? A : V))[r];
  const float ivn = nrm[ten * 32 + j];
  const float icn = nrm[64 + ten * 8192 + (j << 8) + row];
  ushort4 ovn, ocn;
  ovn.x = bf16rne(v.x * ivn); ovn.y = bf16rne(v.y * ivn);
  ovn.z = bf16rne(v.z * ivn); ovn.w = bf16rne(v.w * ivn);
  ocn.x = bf16rne(v.x * icn); ocn.y = bf16rne(v.y * icn);
  ocn.z = bf16rne(v.z * icn); ocn.w = bf16rne(v.w * icn);
  ((ushort4*)(mats + (ten ? 2 * SLOT : 0)))[r]        = ovn;  // V1 or A2
  ((ushort4*)(mats + (ten ? 1 * SLOT : 3 * SLOT)))[r] = ocn;  // A1 or V2
}

// Fused GEMM + exp-sum. Grid (64 rowblocks, 4 sblocks, 2 dirs) = 512 blocks, 256 thr.
// Block tile 128 rows x 64 cols; 4 waves of 64x32; A-fragments in registers (K=256 full);
// col tile (64x256 bf16 = 32KB) staged through XOR-swizzled LDS per j.
__global__ __launch_bounds__(256, 2) void gemm_exp_k(const unsigned short* __restrict__ mats,
                                                     float* __restrict__ part){
  __shared__ unsigned short colbuf[64 * 256];
  const int tid  = threadIdx.x;
  const int lane = tid & 63;
  const int w    = tid >> 6;
  const int wm   = (w & 1) * 64;        // wave row offset in block tile
  const int wn   = (w >> 1) * 32;       // wave col offset
  const int lm   = lane & 15;
  const int kh   = lane >> 4;           // 0..3, k-quad
  const int bx   = blockIdx.x;
  const int s0   = blockIdx.y * 64;
  const int dir  = blockIdx.z;
  const int r0   = bx * 128;
  const int ib   = bx >> 1;             // batch index of this row tile

  const unsigned short* rowsrc  = mats + (dir ? 2 * SLOT : 0) + (size_t)r0 * KD;
  const unsigned short* colbase = mats + (dir ? 3 * SLOT : 1 * SLOT);

  // A-fragments (m = wm + mi*16 + lm, k-chunk = ks*4 + kh) straight from global.
  // Per (mi,ks): wave reads 16 rows x 64B -> coalesced 64B segments.
  s16x8 afr[4][8];
  #pragma unroll
  for (int mi = 0; mi < 4; ++mi){
    const unsigned short* rp = rowsrc + (size_t)(wm + mi * 16 + lm) * KD + kh * 8;
    #pragma unroll
    for (int ks = 0; ks < 8; ++ks)
      afr[mi][ks] = *(const s16x8*)(rp + ks * 32);
  }

  f32x4 acc[4][2];
  #pragma unroll
  for (int mi = 0; mi < 4; ++mi)
    #pragma unroll
    for (int ni = 0; ni < 2; ++ni)
      acc[mi][ni] = f32x4{0.f, 0.f, 0.f, 0.f};

  // Staging: 2048 16B-chunks, 8 per thread. chunk = tid + c*256:
  //   row = (tid>>5) + 8c, kc = tid&31 (c-invariant), swizzle kc' = kc ^ (row&7) (c-invariant).
  const int g_off = ((tid >> 5) << 8) + ((tid & 31) << 3);                       // ushort units
  const int l_off = ((tid >> 5) << 8) + (((tid & 31) ^ ((tid >> 5) & 7)) << 3);

  for (int jj = 0; jj < 31; ++jj){
    const int j = jj + (jj >= ib ? 1 : 0);          // skip j == ib (diag block excluded)
    const unsigned short* cs = colbase + ((size_t)j * 256 + s0) * KD;
    float4 tmp[8];
    #pragma unroll
    for (int c = 0; c < 8; ++c)
      tmp[c] = *(const float4*)(cs + g_off + c * 2048);
    __syncthreads();                                 // prev j's colbuf reads done
    #pragma unroll
    for (int c = 0; c < 8; ++c)
      *(float4*)(&colbuf[l_off + c * 2048]) = tmp[c];
    __syncthreads();                                 // colbuf ready

    f32x4 S[4][2];
    #pragma unroll
    for (int mi = 0; mi < 4; ++mi)
      #pragma unroll
      for (int ni = 0; ni < 2; ++ni)
        S[mi][ni] = f32x4{0.f, 0.f, 0.f, 0.f};

    #pragma unroll
    for (int ks = 0; ks < 8; ++ks){
      s16x8 b[2];
      const int kc = ks * 4 + kh;
      #pragma unroll
      for (int ni = 0; ni < 2; ++ni){
        const int n = wn + ni * 16 + lm;
        b[ni] = *(const s16x8*)(&colbuf[n * 256 + ((kc ^ (n & 7)) << 3)]);
      }
      #pragma unroll
      for (int mi = 0; mi < 4; ++mi)
        #pragma unroll
        for (int ni = 0; ni < 2; ++ni)
          S[mi][ni] = __builtin_amdgcn_mfma_f32_16x16x32_bf16(afr[mi][ks], b[ni], S[mi][ni], 0, 0, 0);
    }
    #pragma unroll
    for (int mi = 0; mi < 4; ++mi)
      #pragma unroll
      for (int ni = 0; ni < 2; ++ni)
        #pragma unroll
        for (int r = 0; r < 4; ++r)
          acc[mi][ni][r] += __expf(S[mi][ni][r]);
  }

  // C/D layout (m89-verified): col = lane&15, row = (lane>>4)*4 + reg
  float* P = part + (size_t)dir * ((size_t)R_TOT * 256);
  #pragma unroll
  for (int mi = 0; mi < 4; ++mi)
    #pragma unroll
    for (int ni = 0; ni < 2; ++ni){
      const int n = s0 + wn + ni * 16 + lm;
      #pragma unroll
      for (int r = 0; r < 4; ++r){
        const int m = r0 + wm + mi * 16 + (kh << 2) + r;
        P[(size_t)m * 256 + n] = acc[mi][ni][r];
      }
    }
}

__global__ void combine_k(const float* __restrict__ part, float* __restrict__ out){
  const int idx = blockIdx.x * 256 + threadIdx.x;   // 524288 float4s
  const float4 a = ((const float4*)part)[idx];
  const float4 b = ((const float4*)(part + (size_t)R_TOT * 256))[idx];
  float4 o;
  o.x = -(logf(1.f + a.x) + logf(1.f + b.x));
  o.y = -(logf(1.f + a.y) + logf(1.f + b.y));
  o.z = -(logf(1.f + a.z) + logf(1.f + b.z));
  o.w = -(logf(1.f + a.w) + logf(1.f + b.w));
  ((float4*)out)[idx] = o;
}

extern "C" void kernel_launch(void* const* d_in, const int* in_sizes, int n_in,
                              void* d_out, int out_size, void* d_ws, size_t ws_size,
                              hipStream_t stream){
  const float* V = (const float*)d_in[2];   // back_VF  (pre_VF/pre_AF unused by reference)
  const float* A = (const float*)d_in[3];   // back_AF
  float* out = (float*)d_out;
  float* nrm = (float*)d_ws;
  unsigned short* mats = (unsigned short*)((char*)d_ws + MATS_OFF);
  float* part = (float*)((char*)d_ws + PART_OFF);

  norms_k<<<dim3(32, 2), 256, 0, stream>>>(V, A, nrm);
  scale_k<<<4096, 256, 0, stream>>>(V, A, nrm, mats);
  gemm_exp_k<<<dim3(64, 4, 2), 256, 0, stream>>>(mats, part);
  combine_k<<<2048, 256, 0, stream>>>(part, out);
}

// Round 2
// 215.811 us; speedup vs baseline: 1.2154x; 1.2154x over previous
//
#include <hip/hip_runtime.h>
#include <cstdint>

// Problem constants: B=32, T=D=256, rows R = B*T = 8192, K = 256.
#define R_TOT 8192
#define KD    256
#define SLOT  ((size_t)R_TOT * KD)            // ushorts per bf16 matrix (2,097,152)
#define MATS_OFF 65792                        // bytes: norms area = (64 + 2*8192) f32
#define PART_OFF (MATS_OFF + (size_t)4 * SLOT * 2)  // 16,843,008
// ws usage: norms (64+16384 f32) + 4 bf16 mats (16 MB) + 2 f32 partials (16 MB) ~= 32.1 MB

typedef float f32x4 __attribute__((ext_vector_type(4)));
typedef short s16x8 __attribute__((ext_vector_type(8)));   // 8 bf16 (4 VGPRs)

__device__ __forceinline__ unsigned short bf16rne(float x){
  union { float f; uint32_t u; } c; c.f = x;
  return (unsigned short)((c.u + 0x7fffu + ((c.u >> 16) & 1u)) >> 16);
}

// nrm layout (f32): [0,32) inv_vnV, [32,64) inv_vnA, [64,64+8192) inv_cnV, then inv_cnA
__global__ void norms_k(const float* __restrict__ V, const float* __restrict__ A,
                        float* __restrict__ nrm){
  const int j = blockIdx.x, ten = blockIdx.y, s = threadIdx.x;
  const float* X = (ten ? A : V) + (size_t)j * (256 * 256) + s;
  float c = 0.f;
  #pragma unroll 8
  for (int t = 0; t < 256; ++t){ float v = X[(size_t)t * 256]; c += v * v; }
  nrm[64 + ten * 8192 + (j << 8) + s] = rsqrtf(c + 1e-18f);   // 1/colnorm
  __shared__ float red[256];
  red[s] = c; __syncthreads();
  for (int off = 128; off > 0; off >>= 1){
    if (s < off) red[s] += red[s + off];
    __syncthreads();
  }
  if (s == 0) nrm[ten * 32 + j] = rsqrtf(red[0] + 1e-18f);    // 1/frobenius
}

// mats slots: 0=V1 (V*ivnV*log2e, dir0 rows), 1=A1 (A*icnA, dir0 cols),
//             2=A2 (A*ivnA*log2e, dir1 rows), 3=V2 (V*icnV, dir1 cols)
// log2e folded into the ROW side so the epilogue exp is a bare v_exp_f32 (exp2).
__global__ void scale_k(const float* __restrict__ V, const float* __restrict__ A,
                        const float* __restrict__ nrm, unsigned short* __restrict__ mats){
  const int idx = blockIdx.x * 256 + threadIdx.x;   // float4 units, 2 tensors
  const int ten = idx >> 19;
  const int r   = idx & 0x7ffff;                    // float4 index within tensor
  const int j   = r >> 14;                          // batch
  const int row = (r >> 6) & 255;                   // row within batch
  const float4 v = ((const float4*)(ten ? A : V))[r];
  const float ivn = nrm[ten * 32 + j] * 1.44269504088896340736f;  // * log2(e)
  const float icn = nrm[64 + ten * 8192 + (j << 8) + row];
  ushort4 ovn, ocn;
  ovn.x = bf16rne(v.x * ivn); ovn.y = bf16rne(v.y * ivn);
  ovn.z = bf16rne(v.z * ivn); ovn.w = bf16rne(v.w * ivn);
  ocn.x = bf16rne(v.x * icn); ocn.y = bf16rne(v.y * icn);
  ocn.z = bf16rne(v.z * icn); ocn.w = bf16rne(v.w * icn);
  ((ushort4*)(mats + (ten ? 2 * SLOT : 0)))[r]        = ovn;  // V1 or A2
  ((ushort4*)(mats + (ten ? 1 * SLOT : 3 * SLOT)))[r] = ocn;  // A1 or V2
}

// Fused GEMM + exp2-sum, v2: NO LDS in the j-loop, no barriers. A-fragments pinned
// in registers (asm reg-barrier prevents rematerialization); B-fragments loaded
// straight from global in MFMA layout each j. Grid dim3(dir=2, sb=4, rb=64):
// round-robin XCD assignment gives each XCD one (dir,sb) stream -> all 64 blocks
// on an XCD read the SAME 32KB col tile per j (L1/L2 locality by construction).
// Epilogue: acc -> LDS transpose -> fully-coalesced float4 stores.
__global__ __launch_bounds__(256, 2) void gemm_exp_k(const unsigned short* __restrict__ mats,
                                                     float* __restrict__ part){
  __shared__ float ebuf[128 * 68];      // 34.8 KB, pad 4 floats -> b128-aligned, <=2-way conflicts
  const int tid  = threadIdx.x;
  const int lane = tid & 63;
  const int w    = tid >> 6;
  const int wm   = (w & 1) * 64;        // wave row offset in block tile (128 rows)
  const int wn   = (w >> 1) * 32;       // wave col offset (64 cols)
  const int lm   = lane & 15;
  const int kh   = lane >> 4;           // 0..3, k-quad
  const int dir  = blockIdx.x;
  const int s0   = blockIdx.y * 64;
  const int rb   = blockIdx.z;
  const int r0   = rb * 128;
  const int ib   = rb >> 1;             // batch index of this row tile

  const unsigned short* rowsrc  = mats + (dir ? 2 * SLOT : 0) + (size_t)r0 * KD;
  const unsigned short* colbase = mats + (dir ? 3 * SLOT : 1 * SLOT);

  // A-fragments (m = wm + mi*16 + lm, k-chunk = ks*4 + kh), one-time load.
  s16x8 afr[4][8];
  #pragma unroll
  for (int mi = 0; mi < 4; ++mi){
    const unsigned short* rp = rowsrc + (size_t)(wm + mi * 16 + lm) * KD + kh * 8;
    #pragma unroll
    for (int ks = 0; ks < 8; ++ks)
      afr[mi][ks] = *(const s16x8*)(rp + ks * 32);
  }
  // Pin: forbids rematerializing these loads inside the j-loop.
  #pragma unroll
  for (int mi = 0; mi < 4; ++mi)
    #pragma unroll
    for (int ks = 0; ks < 8; ++ks)
      asm volatile("" : "+v"(afr[mi][ks]));

  f32x4 acc[4][2];
  #pragma unroll
  for (int mi = 0; mi < 4; ++mi)
    #pragma unroll
    for (int ni = 0; ni < 2; ++ni)
      acc[mi][ni] = f32x4{0.f, 0.f, 0.f, 0.f};

  const unsigned short* wcol = colbase + ((size_t)s0 + wn) * KD;  // wave's col base (row j*256 added per iter)

  for (int jj = 0; jj < 31; ++jj){
    const int j = jj + (jj >= ib ? 1 : 0);          // skip j == ib (diagonal excluded)
    const unsigned short* cs = wcol + (size_t)j * 256 * KD;

    f32x4 S[4][2];
    #pragma unroll
    for (int mi = 0; mi < 4; ++mi)
      #pragma unroll
      for (int ni = 0; ni < 2; ++ni)
        S[mi][ni] = f32x4{0.f, 0.f, 0.f, 0.f};

    #pragma unroll
    for (int ks = 0; ks < 8; ++ks){
      const int ko = (ks * 4 + kh) * 8;
      s16x8 b0 = *(const s16x8*)(cs + (size_t)lm * KD + ko);
      s16x8 b1 = *(const s16x8*)(cs + (size_t)(16 + lm) * KD + ko);
      #pragma unroll
      for (int mi = 0; mi < 4; ++mi){
        S[mi][0] = __builtin_amdgcn_mfma_f32_16x16x32_bf16(afr[mi][ks], b0, S[mi][0], 0, 0, 0);
        S[mi][1] = __builtin_amdgcn_mfma_f32_16x16x32_bf16(afr[mi][ks], b1, S[mi][1], 0, 0, 0);
      }
    }
    #pragma unroll
    for (int mi = 0; mi < 4; ++mi)
      #pragma unroll
      for (int ni = 0; ni < 2; ++ni)
        #pragma unroll
        for (int r = 0; r < 4; ++r)
          acc[mi][ni][r] += __builtin_amdgcn_exp2f(S[mi][ni][r]);  // log2e pre-folded
  }

  // Epilogue: C/D layout (col = lane&15, row = (lane>>4)*4 + reg) -> LDS -> coalesced stores.
  #pragma unroll
  for (int mi = 0; mi < 4; ++mi)
    #pragma unroll
    for (int ni = 0; ni < 2; ++ni){
      const int n = wn + ni * 16 + lm;
      #pragma unroll
      for (int r = 0; r < 4; ++r){
        const int m = wm + mi * 16 + (kh << 2) + r;
        ebuf[m * 68 + n] = acc[mi][ni][r];
      }
    }
  __syncthreads();
  float* P = part + (size_t)dir * ((size_t)R_TOT * 256);
  #pragma unroll
  for (int p = 0; p < 8; ++p){
    const int i   = tid + p * 256;     // 0..2047
    const int row = i >> 4;
    const int c4  = i & 15;
    f32x4 v = *(const f32x4*)(&ebuf[row * 68 + c4 * 4]);
    *(f32x4*)(&P[(size_t)(r0 + row) * 256 + s0 + c4 * 4]) = v;
  }
}

__global__ void combine_k(const float* __restrict__ part, float* __restrict__ out){
  const int idx = blockIdx.x * 256 + threadIdx.x;   // 524288 float4s
  const float4 a = ((const float4*)part)[idx];
  const float4 b = ((const float4*)(part + (size_t)R_TOT * 256))[idx];
  float4 o;
  o.x = -(logf(1.f + a.x) + logf(1.f + b.x));
  o.y = -(logf(1.f + a.y) + logf(1.f + b.y));
  o.z = -(logf(1.f + a.z) + logf(1.f + b.z));
  o.w = -(logf(1.f + a.w) + logf(1.f + b.w));
  ((float4*)out)[idx] = o;
}

extern "C" void kernel_launch(void* const* d_in, const int* in_sizes, int n_in,
                              void* d_out, int out_size, void* d_ws, size_t ws_size,
                              hipStream_t stream){
  const float* V = (const float*)d_in[2];   // back_VF  (pre_VF/pre_AF unused by reference)
  const float* A = (const float*)d_in[3];   // back_AF
  float* out = (float*)d_out;
  float* nrm = (float*)d_ws;
  unsigned short* mats = (unsigned short*)((char*)d_ws + MATS_OFF);
  float* part = (float*)((char*)d_ws + PART_OFF);

  norms_k<<<dim3(32, 2), 256, 0, stream>>>(V, A, nrm);
  scale_k<<<4096, 256, 0, stream>>>(V, A, nrm, mats);
  gemm_exp_k<<<dim3(2, 4, 64), 256, 0, stream>>>(mats, part);
  combine_k<<<2048, 256, 0, stream>>>(part, out);
}

// Round 3
// 159.429 us; speedup vs baseline: 1.6453x; 1.3537x over previous
//
#include <hip/hip_runtime.h>
#include <cstdint>

// Problem constants: B=32, T=D=256, rows R = B*T = 8192, K = 256.
#define R_TOT 8192
#define KD    256
#define SLOT  ((size_t)R_TOT * KD)            // ushorts per bf16 matrix (2,097,152)
#define MATS_OFF 65792                        // bytes: norms area = (64 + 2*8192) f32
#define PART_OFF (MATS_OFF + (size_t)4 * SLOT * 2)  // 16,843,008
// ws usage: norms (64+16384 f32) + 4 bf16 mats (16 MB) + 2 f32 partials (16 MB) ~= 32.1 MB

typedef float f32x4 __attribute__((ext_vector_type(4)));
typedef short s16x8 __attribute__((ext_vector_type(8)));   // 8 bf16 (4 VGPRs)

__device__ __forceinline__ unsigned short bf16rne(float x){
  union { float f; uint32_t u; } c; c.f = x;
  return (unsigned short)((c.u + 0x7fffu + ((c.u >> 16) & 1u)) >> 16);
}

__device__ __forceinline__ void glds16(const void* g, void* l){
  __builtin_amdgcn_global_load_lds((const __attribute__((address_space(1))) uint32_t*)g,
                                   (__attribute__((address_space(3))) uint32_t*)l, 16, 0, 0);
}

// nrm layout (f32): [0,32) inv_vnV, [32,64) inv_vnA, [64,64+8192) inv_cnV, then inv_cnA
__global__ void norms_k(const float* __restrict__ V, const float* __restrict__ A,
                        float* __restrict__ nrm){
  const int j = blockIdx.x, ten = blockIdx.y, s = threadIdx.x;
  const float* X = (ten ? A : V) + (size_t)j * (256 * 256) + s;
  float c = 0.f;
  #pragma unroll 8
  for (int t = 0; t < 256; ++t){ float v = X[(size_t)t * 256]; c += v * v; }
  nrm[64 + ten * 8192 + (j << 8) + s] = rsqrtf(c + 1e-18f);   // 1/colnorm
  __shared__ float red[256];
  red[s] = c; __syncthreads();
  for (int off = 128; off > 0; off >>= 1){
    if (s < off) red[s] += red[s + off];
    __syncthreads();
  }
  if (s == 0) nrm[ten * 32 + j] = rsqrtf(red[0] + 1e-18f);    // 1/frobenius
}

// mats slots: 0=V1 (V*ivnV*log2e, dir0 rows, LINEAR), 1=A1 (A*icnA, dir0 cols, SWIZZLED),
//             2=A2 (A*ivnA*log2e, dir1 rows, LINEAR), 3=V2 (V*icnV, dir1 cols, SWIZZLED)
// Col matrices are pre-swizzled within each 512B row: 16B chunk c stored at c ^ (row & 7),
// so the linear global_load_lds image is bank-conflict-free for MFMA-layout ds_read_b128.
__global__ void scale_k(const float* __restrict__ V, const float* __restrict__ A,
                        const float* __restrict__ nrm, unsigned short* __restrict__ mats){
  const int idx = blockIdx.x * 256 + threadIdx.x;   // float4 units, 2 tensors
  const int ten = idx >> 19;
  const int r   = idx & 0x7ffff;                    // float4 index within tensor
  const int j   = r >> 14;                          // batch
  const int row = (r >> 6) & 255;                   // row within batch
  const float4 v = ((const float4*)(ten ? A : V))[r];
  const float ivn = nrm[ten * 32 + j] * 1.44269504088896340736f;  // * log2(e)
  const float icn = nrm[64 + ten * 8192 + (j << 8) + row];
  ushort4 ovn, ocn;
  ovn.x = bf16rne(v.x * ivn); ovn.y = bf16rne(v.y * ivn);
  ovn.z = bf16rne(v.z * ivn); ovn.w = bf16rne(v.w * ivn);
  ocn.x = bf16rne(v.x * icn); ocn.y = bf16rne(v.y * icn);
  ocn.z = bf16rne(v.z * icn); ocn.w = bf16rne(v.w * icn);
  ((ushort4*)(mats + (ten ? 2 * SLOT : 0)))[r] = ovn;           // rows: linear
  // cols: swizzle 16B chunk (2 ushort4 per chunk) within the 64-float4 row
  const int q   = r & 63;                                       // float4 pos in row
  const int csw = (q >> 1) ^ (row & 7);
  const int rsw = (r & ~63) | (csw << 1) | (q & 1);
  ((ushort4*)(mats + (ten ? 3 * SLOT : 1 * SLOT)))[rsw] = ocn;
}

// v3: m97-style. Block 256 thr = 4 waves; block tile 128 rows x 64 cols; wave tile
// 32 rows x 64 cols -> afr[2][8] = 64 VGPRs (small enough to truly stay resident).
// B col tile (64x256 bf16 = 32 KB) double-buffered in LDS via global_load_lds w=16;
// prefetch j+1 overlaps compute j. Pre-swizzled image => conflict-free ds_read_b128
// with zero in-loop address VALU (8 precomputed bases + imm offsets).
__global__ __launch_bounds__(256, 2) void gemm_exp_k(const unsigned short* __restrict__ mats,
                                                     float* __restrict__ part){
  __shared__ __align__(16) char smem[65536];          // 2 x 32KB B buffers; reused as epilogue buf
  const int tid  = threadIdx.x;
  const int lane = tid & 63;
  const int w    = tid >> 6;
  const int wm   = w * 32;              // wave row offset in 128-row block tile
  const int lm   = lane & 15;
  const int kh   = lane >> 4;           // 0..3
  const int dir  = blockIdx.x;
  const int s0   = blockIdx.y * 64;
  const int rb   = blockIdx.z;
  const int r0   = rb * 128;
  const int ib   = rb >> 1;             // batch index of this row tile (excluded diagonal)

  const unsigned short* rowsrc  = mats + (dir ? 2 * SLOT : 0) + (size_t)r0 * KD;
  const char*           colbase = (const char*)(mats + (dir ? 3 * SLOT : 1 * SLOT));

  // A-fragments (m = wm + mi*16 + lm, k-chunk = ks*4 + kh), one-time load, 64 VGPRs.
  s16x8 afr[2][8];
  #pragma unroll
  for (int mi = 0; mi < 2; ++mi){
    const unsigned short* rp = rowsrc + (size_t)(wm + mi * 16 + lm) * KD + kh * 8;
    #pragma unroll
    for (int ks = 0; ks < 8; ++ks)
      afr[mi][ks] = *(const s16x8*)(rp + ks * 32);
  }
  #pragma unroll
  for (int mi = 0; mi < 2; ++mi)
    #pragma unroll
    for (int ks = 0; ks < 8; ++ks)
      asm volatile("" : "+v"(afr[mi][ks]));

  // ds_read base offsets: addr(ni,ks) = n*512 + ((ks*4+kh) ^ (n&7))*16, n = ni*16+lm.
  // Decompose: pbase (ks even) / palt = pbase^64 (ks odd), + (ks>>1)*128 as imm.
  int pbase[4], palt[4];
  #pragma unroll
  for (int ni = 0; ni < 4; ++ni){
    const int n = ni * 16 + lm;
    const int pb = n * 512 + ((kh ^ (n & 3)) << 4) + (((n >> 2) & 1) << 6);
    pbase[ni] = pb; palt[ni] = pb ^ 64;
  }

  f32x4 acc[2][4];
  #pragma unroll
  for (int mi = 0; mi < 2; ++mi)
    #pragma unroll
    for (int ni = 0; ni < 4; ++ni)
      acc[mi][ni] = f32x4{0.f, 0.f, 0.f, 0.f};

  // Preload j(0) into buffer 0.
  {
    const int j0 = (ib == 0) ? 1 : 0;
    const char* src = colbase + ((size_t)j0 * 256 + s0) * 512;
    #pragma unroll
    for (int c = 0; c < 8; ++c)
      glds16(src + (size_t)(c * 256 + tid) * 16, smem + (c * 256 + w * 64) * 16);
  }
  __syncthreads();

  for (int jj = 0; jj < 31; ++jj){
    if (jj < 30){                                   // prefetch j(jj+1) into other buffer
      const int jn = (jj + 1) + ((jj + 1) >= ib ? 1 : 0);
      const char* src = colbase + ((size_t)jn * 256 + s0) * 512;
      char* dst = smem + (((jj + 1) & 1) << 15);
      #pragma unroll
      for (int c = 0; c < 8; ++c)
        glds16(src + (size_t)(c * 256 + tid) * 16, dst + (c * 256 + w * 64) * 16);
    }

    const char* rbuf = smem + ((jj & 1) << 15);
    f32x4 S[2][4];
    #pragma unroll
    for (int mi = 0; mi < 2; ++mi)
      #pragma unroll
      for (int ni = 0; ni < 4; ++ni)
        S[mi][ni] = f32x4{0.f, 0.f, 0.f, 0.f};

    #pragma unroll
    for (int ks = 0; ks < 8; ++ks){
      const int immo = (ks >> 1) * 128;
      s16x8 b[4];
      #pragma unroll
      for (int ni = 0; ni < 4; ++ni)
        b[ni] = *(const s16x8*)(rbuf + ((ks & 1) ? palt[ni] : pbase[ni]) + immo);
      #pragma unroll
      for (int ni = 0; ni < 4; ++ni){
        S[0][ni] = __builtin_amdgcn_mfma_f32_16x16x32_bf16(afr[0][ks], b[ni], S[0][ni], 0, 0, 0);
        S[1][ni] = __builtin_amdgcn_mfma_f32_16x16x32_bf16(afr[1][ks], b[ni], S[1][ni], 0, 0, 0);
      }
    }
    #pragma unroll
    for (int mi = 0; mi < 2; ++mi)
      #pragma unroll
      for (int ni = 0; ni < 4; ++ni)
        #pragma unroll
        for (int r = 0; r < 4; ++r)
          acc[mi][ni][r] += __builtin_amdgcn_exp2f(S[mi][ni][r]);  // log2e pre-folded

    __syncthreads();   // readers done with rbuf; prefetch (vmcnt) drained for next iter
  }

  // Epilogue: C/D layout (col = lane&15, row = (lane>>4)*4 + reg) -> LDS -> coalesced.
  float* ebuf = (float*)smem;                       // 128*68*4 = 34816 B, fits
  #pragma unroll
  for (int mi = 0; mi < 2; ++mi)
    #pragma unroll
    for (int ni = 0; ni < 4; ++ni){
      const int n = ni * 16 + lm;
      #pragma unroll
      for (int r = 0; r < 4; ++r){
        const int m = wm + mi * 16 + (kh << 2) + r;
        ebuf[m * 68 + n] = acc[mi][ni][r];
      }
    }
  __syncthreads();
  float* P = part + (size_t)dir * ((size_t)R_TOT * 256);
  #pragma unroll
  for (int p = 0; p < 8; ++p){
    const int i   = tid + p * 256;     // 0..2047
    const int row = i >> 4;
    const int c4  = i & 15;
    f32x4 v = *(const f32x4*)(&ebuf[row * 68 + c4 * 4]);
    *(f32x4*)(&P[(size_t)(r0 + row) * 256 + s0 + c4 * 4]) = v;
  }
}

__global__ void combine_k(const float* __restrict__ part, float* __restrict__ out){
  const int idx = blockIdx.x * 256 + threadIdx.x;   // 524288 float4s
  const float4 a = ((const float4*)part)[idx];
  const float4 b = ((const float4*)(part + (size_t)R_TOT * 256))[idx];
  float4 o;
  o.x = -(logf(1.f + a.x) + logf(1.f + b.x));
  o.y = -(logf(1.f + a.y) + logf(1.f + b.y));
  o.z = -(logf(1.f + a.z) + logf(1.f + b.z));
  o.w = -(logf(1.f + a.w) + logf(1.f + b.w));
  ((float4*)out)[idx] = o;
}

extern "C" void kernel_launch(void* const* d_in, const int* in_sizes, int n_in,
                              void* d_out, int out_size, void* d_ws, size_t ws_size,
                              hipStream_t stream){
  const float* V = (const float*)d_in[2];   // back_VF  (pre_VF/pre_AF unused by reference)
  const float* A = (const float*)d_in[3];   // back_AF
  float* out = (float*)d_out;
  float* nrm = (float*)d_ws;
  unsigned short* mats = (unsigned short*)((char*)d_ws + MATS_OFF);
  float* part = (float*)((char*)d_ws + PART_OFF);

  norms_k<<<dim3(32, 2), 256, 0, stream>>>(V, A, nrm);
  scale_k<<<4096, 256, 0, stream>>>(V, A, nrm, mats);
  gemm_exp_k<<<dim3(2, 4, 64), 256, 0, stream>>>(mats, part);
  combine_k<<<2048, 256, 0, stream>>>(part, out);
}

// Round 4
// 147.459 us; speedup vs baseline: 1.7788x; 1.0812x over previous
//
#include <hip/hip_runtime.h>
#include <cstdint>

// Problem constants: B=32, T=D=256, rows R = B*T = 8192, K = 256.
#define R_TOT 8192
#define KD    256
#define SLOT  ((size_t)R_TOT * KD)            // elements per bf16 matrix (2,097,152)
// ws layout (bytes):
#define IVN_OFF  0                            // 64 f32: 1/frobenius-norm [ten][j]
#define ICN_OFF  256                          // 2*8192 f32: 1/col-norm [ten][j][s]
#define CSQ_OFF  (ICN_OFF + 65536)            // 2*8192 f32: col sum-of-squares (atomic)
#define MATS_OFF (CSQ_OFF + 65536)            // 2 bf16 mats (Vb, Ab), swizzled, 8.4 MB
#define PART_OFF (MATS_OFF + (size_t)2 * SLOT * 2)  // 2 bf16 partials, 8.4 MB

typedef float f32x4 __attribute__((ext_vector_type(4)));
typedef short s16x8 __attribute__((ext_vector_type(8)));   // 8 bf16 (4 VGPRs)

__device__ __forceinline__ unsigned short bf16rne(float x){
  union { float f; uint32_t u; } c; c.f = x;
  return (unsigned short)((c.u + 0x7fffu + ((c.u >> 16) & 1u)) >> 16);
}
__device__ __forceinline__ float bf2f(unsigned short u){
  union { uint32_t u; float f; } c; c.u = ((uint32_t)u) << 16; return c.f;
}
__device__ __forceinline__ void glds16(const void* g, void* l){
  __builtin_amdgcn_global_load_lds((const __attribute__((address_space(1))) uint32_t*)g,
                                   (__attribute__((address_space(3))) uint32_t*)l, 16, 0, 0);
}

__global__ void zero_k(float* __restrict__ p){
  p[blockIdx.x * 256 + threadIdx.x] = 0.f;     // 16384 colsq entries
}

// Cast V,A -> bf16 swizzled images AND accumulate column sum-of-squares.
// Image row r = j*256 + t, k-dim = d; 16B chunk c of row r stored at c ^ (r&7).
// Grid (tc=8, j=32, ten=2), 256 thr. Block covers 32 t-rows x 256 d.
__global__ void cast_ns_k(const float* __restrict__ V, const float* __restrict__ A,
                          unsigned short* __restrict__ mats, float* __restrict__ csq){
  const int tc = blockIdx.x, j = blockIdx.y, ten = blockIdx.z;
  const int tid = threadIdx.x;
  const int chunk = tid & 31;                  // d-chunk (8 floats)
  const int tsub  = tid >> 5;                  // 0..7
  const float* X = (ten ? A : V) + (size_t)j * 65536;
  unsigned short* M = mats + (size_t)ten * SLOT + (size_t)j * 65536;
  float cs[8];
  #pragma unroll
  for (int e = 0; e < 8; ++e) cs[e] = 0.f;
  #pragma unroll
  for (int tt = 0; tt < 4; ++tt){
    const int t = tc * 32 + tt * 8 + tsub;
    const float4 p0 = *(const float4*)(X + t * 256 + chunk * 8);
    const float4 p1 = *(const float4*)(X + t * 256 + chunk * 8 + 4);
    cs[0] += p0.x * p0.x; cs[1] += p0.y * p0.y; cs[2] += p0.z * p0.z; cs[3] += p0.w * p0.w;
    cs[4] += p1.x * p1.x; cs[5] += p1.y * p1.y; cs[6] += p1.z * p1.z; cs[7] += p1.w * p1.w;
    s16x8 o;
    o[0] = (short)bf16rne(p0.x); o[1] = (short)bf16rne(p0.y);
    o[2] = (short)bf16rne(p0.z); o[3] = (short)bf16rne(p0.w);
    o[4] = (short)bf16rne(p1.x); o[5] = (short)bf16rne(p1.y);
    o[6] = (short)bf16rne(p1.z); o[7] = (short)bf16rne(p1.w);
    *(s16x8*)(M + (size_t)t * 256 + ((chunk ^ (t & 7)) << 3)) = o;
  }
  __shared__ float red[8][256];
  #pragma unroll
  for (int e = 0; e < 8; ++e) red[tsub][chunk * 8 + e] = cs[e];
  __syncthreads();
  float s = 0.f;
  #pragma unroll
  for (int g = 0; g < 8; ++g) s += red[g][tid];
  atomicAdd(&csq[ten * 8192 + j * 256 + tid], s);
}

// Finish norms: icn = rsqrt(colsq+eps), ivn = rsqrt(sum colsq + eps). Grid (32, 2).
__global__ void nreduce_k(const float* __restrict__ csq, float* __restrict__ ivn,
                          float* __restrict__ icn){
  const int j = blockIdx.x, ten = blockIdx.y, s = threadIdx.x;
  const float c = csq[ten * 8192 + j * 256 + s];
  icn[ten * 8192 + j * 256 + s] = rsqrtf(c + 1e-18f);
  __shared__ float red[256];
  red[s] = c; __syncthreads();
  for (int off = 128; off > 0; off >>= 1){
    if (s < off) red[s] += red[s + off];
    __syncthreads();
  }
  if (s == 0) ivn[ten * 32 + j] = rsqrtf(red[0] + 1e-18f);
}

// v4: wave tile 64m x 32n (B-reuse doubled); A-frags (128 VGPRs) from swizzled global;
// norm scales applied in the exp epilogue (images are unscaled/shared between dirs);
// B col tile double-buffered LDS via global_load_lds w=16; bf16 part output.
__global__ __launch_bounds__(256, 2) void gemm_exp_k(const unsigned short* __restrict__ mats,
                                                     const float* __restrict__ ivn,
                                                     const float* __restrict__ icn,
                                                     unsigned short* __restrict__ part){
  __shared__ __align__(16) char smem[65536];          // 2 x 32KB B buffers; epilogue reuse
  const int tid  = threadIdx.x;
  const int lane = tid & 63;
  const int w    = tid >> 6;
  const int wm   = (w & 1) * 64;        // wave row offset in 128-row block tile
  const int wn   = (w >> 1) * 32;       // wave col offset in 64-col block tile
  const int lm   = lane & 15;
  const int kh   = lane >> 4;           // 0..3
  const int dir  = blockIdx.x;
  const int s0   = blockIdx.y * 64;
  const int rb   = blockIdx.z;
  const int r0   = rb * 128;
  const int ib   = rb >> 1;             // batch index of this row tile (excluded diagonal)

  const unsigned short* rowmat = mats + (size_t)dir * SLOT;        // dir0: Vb, dir1: Ab
  const unsigned short* colmat = mats + (size_t)(1 - dir) * SLOT;  // the other one
  const float sivn = ivn[dir * 32 + ib] * 1.44269504088896340736f; // row scale * log2e
  const float* icnb = icn + (size_t)(1 - dir) * 8192 + s0 + wn;    // col scales

  // A-fragments (m = r0+wm+mi*16+lm, chunk = (ks*4+kh) ^ (lm&7)) from swizzled image.
  s16x8 afr[4][8];
  #pragma unroll
  for (int mi = 0; mi < 4; ++mi){
    const unsigned short* rp = rowmat + (size_t)(r0 + wm + mi * 16 + lm) * 256;
    #pragma unroll
    for (int ks = 0; ks < 8; ++ks)
      afr[mi][ks] = *(const s16x8*)(rp + (((ks * 4 + kh) ^ (lm & 7)) << 3));
  }
  #pragma unroll
  for (int mi = 0; mi < 4; ++mi)
    #pragma unroll
    for (int ks = 0; ks < 8; ++ks)
      asm volatile("" : "+v"(afr[mi][ks]));

  // ds_read bases: addr(ni,ks) = n*512 + (((ks*4+kh) ^ (n&7))<<4), n = wn+ni*16+lm.
  int pbase[2], palt[2];
  #pragma unroll
  for (int ni = 0; ni < 2; ++ni){
    const int n = wn + ni * 16 + lm;
    const int pb = n * 512 + ((kh ^ (n & 3)) << 4) + (((n >> 2) & 1) << 6);
    pbase[ni] = pb; palt[ni] = pb ^ 64;
  }

  f32x4 acc[4][2];
  #pragma unroll
  for (int mi = 0; mi < 4; ++mi)
    #pragma unroll
    for (int ni = 0; ni < 2; ++ni)
      acc[mi][ni] = f32x4{0.f, 0.f, 0.f, 0.f};

  // Preload j(0) into buffer 0.
  {
    const int j0 = (ib == 0) ? 1 : 0;
    const char* src = (const char*)colmat + ((size_t)j0 * 256 + s0) * 512;
    #pragma unroll
    for (int c = 0; c < 8; ++c)
      glds16(src + (size_t)(c * 256 + tid) * 16, smem + (c * 256 + w * 64) * 16);
  }
  __syncthreads();

  for (int jj = 0; jj < 31; ++jj){
    const int j = jj + (jj >= ib ? 1 : 0);
    if (jj < 30){
      const int jn = (jj + 1) + ((jj + 1) >= ib ? 1 : 0);
      const char* src = (const char*)colmat + ((size_t)jn * 256 + s0) * 512;
      char* dst = smem + (((jj + 1) & 1) << 15);
      #pragma unroll
      for (int c = 0; c < 8; ++c)
        glds16(src + (size_t)(c * 256 + tid) * 16, dst + (c * 256 + w * 64) * 16);
    }

    // per-j column scales (2 scalars/lane; loads issue early, used after MFMAs)
    const float csc0 = sivn * icnb[j * 256 + lm];
    const float csc1 = sivn * icnb[j * 256 + 16 + lm];

    const char* rbuf = smem + ((jj & 1) << 15);
    f32x4 S[4][2];
    #pragma unroll
    for (int mi = 0; mi < 4; ++mi)
      #pragma unroll
      for (int ni = 0; ni < 2; ++ni)
        S[mi][ni] = f32x4{0.f, 0.f, 0.f, 0.f};

    #pragma unroll
    for (int ks = 0; ks < 8; ++ks){
      const int immo = (ks >> 1) * 128;
      s16x8 b0 = *(const s16x8*)(rbuf + ((ks & 1) ? palt[0] : pbase[0]) + immo);
      s16x8 b1 = *(const s16x8*)(rbuf + ((ks & 1) ? palt[1] : pbase[1]) + immo);
      #pragma unroll
      for (int mi = 0; mi < 4; ++mi){
        S[mi][0] = __builtin_amdgcn_mfma_f32_16x16x32_bf16(afr[mi][ks], b0, S[mi][0], 0, 0, 0);
        S[mi][1] = __builtin_amdgcn_mfma_f32_16x16x32_bf16(afr[mi][ks], b1, S[mi][1], 0, 0, 0);
      }
    }
    #pragma unroll
    for (int mi = 0; mi < 4; ++mi)
      #pragma unroll
      for (int r = 0; r < 4; ++r){
        acc[mi][0][r] += __builtin_amdgcn_exp2f(S[mi][0][r] * csc0);
        acc[mi][1][r] += __builtin_amdgcn_exp2f(S[mi][1][r] * csc1);
      }

    __syncthreads();   // readers done with rbuf; prefetch drained for next iter
  }

  // Epilogue: C/D layout (col = lane&15, row = (lane>>4)*4 + reg) -> LDS -> coalesced bf16.
  unsigned short* ebuf = (unsigned short*)smem;       // [128][72] ushorts = 18 KB
  #pragma unroll
  for (int mi = 0; mi < 4; ++mi)
    #pragma unroll
    for (int ni = 0; ni < 2; ++ni){
      const int n = wn + ni * 16 + lm;
      #pragma unroll
      for (int r = 0; r < 4; ++r){
        const int m = wm + mi * 16 + (kh << 2) + r;
        ebuf[m * 72 + n] = bf16rne(acc[mi][ni][r]);
      }
    }
  __syncthreads();
  unsigned short* P = part + (size_t)dir * SLOT;
  #pragma unroll
  for (int p = 0; p < 4; ++p){
    const int q   = tid + p * 256;     // 0..1023 (16B units of the 128x64 tile)
    const int row = q >> 3;
    const int c8  = q & 7;
    s16x8 v = *(const s16x8*)(&ebuf[row * 72 + c8 * 8]);
    *(s16x8*)(&P[(size_t)(r0 + row) * 256 + s0 + c8 * 8]) = v;
  }
}

__global__ void combine_k(const unsigned short* __restrict__ part, float* __restrict__ out){
  const int idx = blockIdx.x * 256 + threadIdx.x;   // 262144 ushort8 units
  s16x8 a = ((const s16x8*)part)[idx];
  s16x8 b = ((const s16x8*)(part + (size_t)R_TOT * 256))[idx];
  float4 o0, o1;
  o0.x = -(__logf(1.f + bf2f((unsigned short)a[0])) + __logf(1.f + bf2f((unsigned short)b[0])));
  o0.y = -(__logf(1.f + bf2f((unsigned short)a[1])) + __logf(1.f + bf2f((unsigned short)b[1])));
  o0.z = -(__logf(1.f + bf2f((unsigned short)a[2])) + __logf(1.f + bf2f((unsigned short)b[2])));
  o0.w = -(__logf(1.f + bf2f((unsigned short)a[3])) + __logf(1.f + bf2f((unsigned short)b[3])));
  o1.x = -(__logf(1.f + bf2f((unsigned short)a[4])) + __logf(1.f + bf2f((unsigned short)b[4])));
  o1.y = -(__logf(1.f + bf2f((unsigned short)a[5])) + __logf(1.f + bf2f((unsigned short)b[5])));
  o1.z = -(__logf(1.f + bf2f((unsigned short)a[6])) + __logf(1.f + bf2f((unsigned short)b[6])));
  o1.w = -(__logf(1.f + bf2f((unsigned short)a[7])) + __logf(1.f + bf2f((unsigned short)b[7])));
  ((float4*)out)[idx * 2]     = o0;
  ((float4*)out)[idx * 2 + 1] = o1;
}

extern "C" void kernel_launch(void* const* d_in, const int* in_sizes, int n_in,
                              void* d_out, int out_size, void* d_ws, size_t ws_size,
                              hipStream_t stream){
  const float* V = (const float*)d_in[2];   // back_VF  (pre_VF/pre_AF unused by reference)
  const float* A = (const float*)d_in[3];   // back_AF
  float* out = (float*)d_out;
  float* ivn = (float*)((char*)d_ws + IVN_OFF);
  float* icn = (float*)((char*)d_ws + ICN_OFF);
  float* csq = (float*)((char*)d_ws + CSQ_OFF);
  unsigned short* mats = (unsigned short*)((char*)d_ws + MATS_OFF);
  unsigned short* part = (unsigned short*)((char*)d_ws + PART_OFF);

  zero_k<<<64, 256, 0, stream>>>(csq);
  cast_ns_k<<<dim3(8, 32, 2), 256, 0, stream>>>(V, A, mats, csq);
  nreduce_k<<<dim3(32, 2), 256, 0, stream>>>(csq, ivn, icn);
  gemm_exp_k<<<dim3(2, 4, 64), 256, 0, stream>>>(mats, ivn, icn, part);
  combine_k<<<1024, 256, 0, stream>>>(part, out);
}